// Round 4
// baseline (129.661 us; speedup 1.0000x reference)
//
#include <hip/hip_runtime.h>
#include <hip/hip_bf16.h>
#include <hip/hip_cooperative_groups.h>

namespace cg = cooperative_groups;

// FrameReducer: N=16, T=2048, C=512, V=500 — single cooperative kernel.
//
// Phase 1 (all blocks): keep[t] = (ctc[n,t,blank] < log(0.9)) && (t < x_lens[n])
//   wave __ballot -> masks[chunk] (u64) + counts[chunk] (popcount), chunk = (n*T+t)/64.
// grid.sync()
// Phase 2 (block 0 only): per-seq exclusive scan of counts -> in-place chunk
//   bases; lens[n]; lens_out[n] (float tail of d_out). Then one thread per
//   chunk walks its mask LSB-first emitting idx[n*T + base++] = t (stable).
// grid.sync()
// Phase 3 (all blocks): grid-stride over output rows (n,p), 2 rows per block
//   iteration (256 thr / 128 f4-per-row). out = (p < lens[n]) ? x[n, idx, :] : 0.

__global__ void fused_kernel(const float* __restrict__ x,
                             const void* __restrict__ x_lens_raw,
                             const float* __restrict__ ctc,
                             const int* __restrict__ blank_id_p,
                             int N, int T, int V, int C, int Tp,
                             unsigned long long* __restrict__ masks,
                             int* __restrict__ counts,
                             int* __restrict__ idx,
                             int* __restrict__ lens,
                             float* __restrict__ out,
                             float* __restrict__ lens_out) {
    cg::grid_group grid = cg::this_grid();
    const int tid = threadIdx.x;                 // 256
    const int NT = N * T;
    const int NCPS = T >> 6;                     // chunks per sequence (32)

    // ---- phase 1: mask + ballot ----
    const int* li = (const int*)x_lens_raw;
    const bool is64 = (N > 1 && li[1] == 0);     // int64 layout detection
    const int blank = *blank_id_p;
    const float thr = -0.10536052f;              // float32(log(0.9))

    for (int base = blockIdx.x * 256; base < NT; base += gridDim.x * 256) {
        int gidx = base + tid;
        bool keep = false;
        if (gidx < NT) {
            int n = gidx / T;
            int t = gidx - n * T;
            long long L = is64 ? ((const long long*)x_lens_raw)[n]
                               : (long long)li[n];
            float v = ctc[(long long)gidx * V + blank];
            keep = (v < thr) && ((long long)t < L);
        }
        unsigned long long bal = __ballot(keep);
        if ((tid & 63) == 0 && gidx < NT) {
            int chunk = gidx >> 6;
            masks[chunk] = bal;
            counts[chunk] = __popcll(bal);
        }
    }

    grid.sync();

    // ---- phase 2: scan + idx emit (block 0) ----
    if (blockIdx.x == 0) {
        for (int n = tid; n < N; n += blockDim.x) {
            int acc = 0;
            for (int c = 0; c < NCPS; ++c) {
                int cc = counts[n * NCPS + c];
                counts[n * NCPS + c] = acc;      // in-place exclusive bases
                acc += cc;
            }
            lens[n] = acc;
            lens_out[n] = (float)acc;
        }
        __syncthreads();
        for (int chunk = tid; chunk < N * NCPS; chunk += blockDim.x) {
            unsigned long long m = masks[chunk];
            int base = counts[chunk];
            int n = chunk / NCPS;
            int t0 = (chunk - n * NCPS) << 6;
            int* my = idx + n * T;
            while (m) {
                int b = __builtin_ctzll(m);
                my[base++] = t0 + b;
                m &= (m - 1);
            }
        }
    }

    grid.sync();

    // ---- phase 3: gather ----
    const int f4PerRow = C >> 2;                 // 128
    const int sub = tid / f4PerRow;              // 0..1
    const int c4 = tid - sub * f4PerRow;
    const long long totalRows = (long long)N * Tp;
    for (long long r = (long long)blockIdx.x * 2 + sub; r < totalRows;
         r += (long long)gridDim.x * 2) {
        int n = (int)(r / Tp);
        int p = (int)(r - (long long)n * Tp);
        float4 v = make_float4(0.f, 0.f, 0.f, 0.f);
        if (p < lens[n]) {
            int tsrc = idx[n * T + p];
            const float4* src = (const float4*)(x + (long long)(n * T + tsrc) * C);
            v = src[c4];
        }
        ((float4*)out)[r * f4PerRow + c4] = v;
    }
}

extern "C" void kernel_launch(void* const* d_in, const int* in_sizes, int n_in,
                              void* d_out, int out_size, void* d_ws, size_t ws_size,
                              hipStream_t stream) {
    const float* x        = (const float*)d_in[0];
    const void*  x_lens   = d_in[1];
    const float* ctc      = (const float*)d_in[2];
    const int*   blank_id = (const int*)d_in[3];

    int N = in_sizes[1];                // 16
    int C = 512;
    int V = 500;
    int T = in_sizes[0] / (N * C);      // 2048
    int Tp = (out_size - N) / (N * C);  // T'
    const int NCPS = T >> 6;            // 32

    unsigned long long* masks = (unsigned long long*)d_ws;        // [N*NCPS]
    int* counts = (int*)(masks + (long long)N * NCPS);            // [N*NCPS]
    int* idx    = counts + (long long)N * NCPS;                   // [N][T]
    int* lens   = idx + (long long)N * T;                         // [N]

    float* out      = (float*)d_out;                              // [N][Tp][C]
    float* lens_out = out + (long long)N * Tp * C;                // [N] float

    void* args[] = { (void*)&x, (void*)&x_lens, (void*)&ctc, (void*)&blank_id,
                     (void*)&N, (void*)&T, (void*)&V, (void*)&C, (void*)&Tp,
                     (void*)&masks, (void*)&counts, (void*)&idx, (void*)&lens,
                     (void*)&out, (void*)&lens_out };

    hipLaunchCooperativeKernel((const void*)fused_kernel,
                               dim3(512), dim3(256), args, 0, stream);
}

// Round 5
// 19.054 us; speedup vs baseline: 6.8050x; 6.8050x over previous
//
#include <hip/hip_runtime.h>
#include <hip/hip_bf16.h>

// FrameReducer: N=16, T=2048, C=512, V=500 — two dispatches.
//
// Kernel 1 (compact): N blocks x 1024 threads. keep[t] = (ctc[n,t,blank] <
//   log(0.9)) && (t < x_lens[n]); wave ballots -> per-chunk counts in LDS ->
//   thread-0 exclusive scan (32 entries, once per block) -> stable idx emit
//   (idx[n*T + pos] = t). Writes lens[n] and float lens tail of d_out.
// Kernel 2 (gather): grid (ceil(Tp/4), N), 256 threads. 4 rows/block,
//   64 lanes/row x 32B (2 contiguous float4). n from blockIdx.y (no int div);
//   lens[n] scalar; idx[n*T+p] wave-uniform L1 broadcast.
//   out row = (p < lens[n]) ? x[n, idx, :] : 0  (zero tail required: harness
//   poisons d_out once and never re-poisons).

__global__ void compact_kernel(const float* __restrict__ ctc,
                               const void* __restrict__ x_lens_raw,
                               const int* __restrict__ blank_id_p,
                               int T, int V, int N,
                               int* __restrict__ idx,
                               int* __restrict__ lens,
                               float* __restrict__ lens_out) {
    const int n    = blockIdx.x;
    const int tid  = threadIdx.x;          // 1024 threads = 16 waves
    const int lane = tid & 63;
    const int wid  = tid >> 6;
    const int ITERS = (T + 1023) >> 10;    // 2 for T=2048
    const int NCHUNK = ITERS * 16;         // 32

    __shared__ int wcnt[64];
    __shared__ int pfx[65];

    // x_lens dtype detection: values in [1,T], never 0 -> int64 layout iff
    // int32 view at odd index is 0.
    const int* li = (const int*)x_lens_raw;
    long long L;
    if (N > 1 && li[1] == 0) {
        L = ((const long long*)x_lens_raw)[n];
    } else {
        L = (long long)li[n];
    }

    const int blank = *blank_id_p;
    const float thr = -0.10536052f;        // float32(log(0.9))

    unsigned long long bal[4];
    #pragma unroll
    for (int j = 0; j < 4; ++j) bal[j] = 0ull;

    for (int j = 0; j < ITERS; ++j) {
        int t = (j << 10) + tid;
        bool keep = false;
        if (t < T) {
            float v = ctc[((long long)n * T + t) * V + blank];
            keep = (v < thr) && ((long long)t < L);
        }
        bal[j] = __ballot(keep);
        if (lane == 0) wcnt[j * 16 + wid] = __popcll(bal[j]);
    }
    __syncthreads();

    if (tid == 0) {
        int acc = 0;
        for (int c = 0; c < NCHUNK; ++c) { pfx[c] = acc; acc += wcnt[c]; }
        pfx[NCHUNK] = acc;
        lens[n] = acc;
        lens_out[n] = (float)acc;
    }
    __syncthreads();

    int* my_idx = idx + (long long)n * T;
    for (int j = 0; j < ITERS; ++j) {
        int t = (j << 10) + tid;
        unsigned long long b = bal[j];
        if (b & (1ull << lane)) {
            int rank = __popcll(b & ((1ull << lane) - 1ull));
            my_idx[pfx[j * 16 + wid] + rank] = t;
        }
    }
}

__global__ __launch_bounds__(256) void gather_kernel(
        const float* __restrict__ x,
        const int* __restrict__ idx,
        const int* __restrict__ lens,
        float* __restrict__ out,
        int Tp, int T) {
    const int C = 512;
    const int n    = blockIdx.y;
    const int sub  = threadIdx.x >> 6;           // row within block (0..3)
    const int lane = threadIdx.x & 63;           // 64 lanes x 32B = 2KB row
    const int p    = blockIdx.x * 4 + sub;
    if (p >= Tp) return;

    const int L = lens[n];                       // block-uniform scalar
    float4 a = make_float4(0.f, 0.f, 0.f, 0.f);
    float4 b = a;
    if (p < L) {
        int tsrc = idx[n * T + p];               // wave-uniform, L1 broadcast
        const float4* src = (const float4*)(x + ((long long)n * T + tsrc) * C);
        a = src[lane * 2];
        b = src[lane * 2 + 1];
    }
    float4* dst = (float4*)(out + ((long long)n * Tp + p) * C);
    dst[lane * 2]     = a;
    dst[lane * 2 + 1] = b;
}

extern "C" void kernel_launch(void* const* d_in, const int* in_sizes, int n_in,
                              void* d_out, int out_size, void* d_ws, size_t ws_size,
                              hipStream_t stream) {
    const float* x        = (const float*)d_in[0];
    const void*  x_lens   = d_in[1];
    const float* ctc      = (const float*)d_in[2];
    const int*   blank_id = (const int*)d_in[3];

    const int N = in_sizes[1];               // 16
    const int C = 512;
    const int V = 500;
    const int T = in_sizes[0] / (N * C);     // 2048
    const int Tp = (out_size - N) / (N * C); // T'

    int* idx  = (int*)d_ws;                  // [N][T]
    int* lens = idx + (long long)N * T;      // [N]

    float* out      = (float*)d_out;                   // [N][Tp][C]
    float* lens_out = out + (long long)N * Tp * C;     // [N] float

    compact_kernel<<<N, 1024, 0, stream>>>(ctc, x_lens, blank_id, T, V, N,
                                           idx, lens, lens_out);

    dim3 ggrid((Tp + 3) / 4, N);
    gather_kernel<<<ggrid, 256, 0, stream>>>(x, idx, lens, out, Tp, T);
}